// Round 1
// baseline (6382.239 us; speedup 1.0000x reference)
//
#include <hip/hip_runtime.h>

#define NN 1024
#define NM1 1023
#define DXF 100.0f
#define EPSF 1e-20f

// FD * (RHO*G)^3, computed in double like Python, cast to f32 once (JAX weak-scalar semantics)
constexpr double RG_ = 910.0 * 9.81;
constexpr float CFD = (float)(1e-16 * (RG_ * RG_ * RG_));

__device__ __forceinline__ float wave_max(float v) {
    #pragma unroll
    for (int off = 32; off > 0; off >>= 1)
        v = fmaxf(v, __shfl_down(v, off, 64));
    return v;
}

// scal[0] = maxD bits (uint), scal[1] = t, scal[2] = dt
__global__ void k_init(const float* __restrict__ Hin, const float* __restrict__ Ztopo,
                       float* __restrict__ H, float* __restrict__ Zs, float* scal) {
    int idx = blockIdx.x * blockDim.x + threadIdx.x;
    if (idx < NN * NN) {
        float h = Hin[idx];
        H[idx] = h;
        Zs[idx] = Ztopo[idx] + h;
    }
    if (idx == 0) {
        ((unsigned int*)scal)[0] = 0u;  // maxD = +0.0f
        scal[1] = 1880.0f;              // t = T0
    }
}

__global__ void k_diffusivity(const float* __restrict__ H, const float* __restrict__ Zs,
                              float* __restrict__ D, float* scal) {
    int j = blockIdx.x * blockDim.x + threadIdx.x;
    int i = blockIdx.y * blockDim.y + threadIdx.y;
    float d = 0.0f;
    if (i < NM1 && j < NM1) {
        const float* Zr0 = Zs + i * NN;
        const float* Zr1 = Zr0 + NN;
        const float* Hr0 = H + i * NN;
        const float* Hr1 = Hr0 + NN;
        // reference op order: 0.25*(((H00 + H11) + H01) + H10)
        float havg = 0.25f * (((Hr0[j] + Hr1[j + 1]) + Hr0[j + 1]) + Hr1[j]);
        float sx = 0.5f * ((Zr0[j + 1] - Zr0[j]) / DXF + (Zr1[j + 1] - Zr1[j]) / DXF);
        float sy = 0.5f * ((Zr1[j] - Zr0[j]) / DXF + (Zr1[j + 1] - Zr0[j + 1]) / DXF);
        float sn = sqrtf(sx * sx + sy * sy + EPSF);
        float h2 = havg * havg;
        float h4 = h2 * h2;
        float h5 = h4 * havg;   // pow(x,5) by squaring, like XLA
        d = CFD * h5 * (sn * sn) + EPSF;
        D[i * NM1 + j] = d;
    }
    float m = wave_max(d);
    int lane = (threadIdx.y * blockDim.x + threadIdx.x) & 63;
    if (lane == 0) atomicMax((unsigned int*)scal, __float_as_uint(m));  // d >= 0: uint order == float order
}

__global__ void k_dt(float* scal) {
    float maxD = __uint_as_float(((unsigned int*)scal)[0]);
    float dt = fminf(10000.0f / (2.7f * maxD), 1.0f);
    float t = scal[1];
    if (!(t < 1900.0f)) dt = 0.0f;
    scal[2] = dt;
    scal[1] = t + dt;
    ((unsigned int*)scal)[0] = 0u;  // reset max for next step
}

__global__ void k_update(const float* __restrict__ D, const float* __restrict__ Zs,
                         const float* __restrict__ Zela, const float* __restrict__ Ztopo,
                         float* __restrict__ H, float* __restrict__ Zn,
                         const float* scal) {
    int j = blockIdx.x * blockDim.x + threadIdx.x;
    int i = blockIdx.y * blockDim.y + threadIdx.y;
    if (i >= NN || j >= NN) return;
    int idx = i * NN + j;
    float h = H[idx];
    if (i >= 1 && i <= NN - 2 && j >= 1 && j <= NN - 2) {
        float dt = scal[2];
        const float* Drm = D + (i - 1) * NM1;
        const float* Dr0 = D + i * NM1;
        float Dmm = Drm[j - 1], Dm0 = Drm[j];
        float D0m = Dr0[j - 1], D00 = Dr0[j];
        const float* Zrm = Zs + (i - 1) * NN;
        const float* Zr0 = Zs + i * NN;
        const float* Zrp = Zs + (i + 1) * NN;
        float z00 = Zr0[j];
        // qx[i-1][j], qx[i-1][j-1]
        float qxr = -(0.5f * (Dm0 + D00)) * (Zr0[j + 1] - z00) / DXF;
        float qxl = -(0.5f * (Dmm + D0m)) * (z00 - Zr0[j - 1]) / DXF;
        // qy[i][j-1], qy[i-1][j-1]
        float qyd = -(0.5f * (D0m + D00)) * (Zrp[j] - z00) / DXF;
        float qyu = -(0.5f * (Dmm + Dm0)) * (z00 - Zrm[j]) / DXF;
        float dHdt = -((qxr - qxl) / DXF + (qyd - qyu) / DXF);
        float b = fminf(1e-3f * (z00 - Zela[idx]), 0.3f);
        h = h + dt * (dHdt + b);
    }
    h = fmaxf(h, 0.0f);
    H[idx] = h;
    Zn[idx] = Ztopo[idx] + h;
}

extern "C" void kernel_launch(void* const* d_in, const int* in_sizes, int n_in,
                              void* d_out, int out_size, void* d_ws, size_t ws_size,
                              hipStream_t stream) {
    const float* Zela  = (const float*)d_in[0];
    const float* Ztopo = (const float*)d_in[1];
    const float* Hin   = (const float*)d_in[2];
    float* H = (float*)d_out;

    float* w    = (float*)d_ws;
    float* scal = w;                      // 16 floats reserved
    float* Dbuf = w + 16;                 // (N-1)^2, padded into N^2 slot
    float* ZA   = w + 16 + NN * NN;
    float* ZB   = ZA + NN * NN;

    dim3 b1(256), g1((NN * NN + 255) / 256);
    k_init<<<g1, b1, 0, stream>>>(Hin, Ztopo, H, ZA, scal);

    dim3 blk(64, 4);
    dim3 gD((NM1 + 63) / 64, (NM1 + 3) / 4);
    dim3 gU((NN + 63) / 64, (NN + 3) / 4);

    float* zc = ZA;
    float* zn = ZB;
    for (int s = 0; s < 32; ++s) {
        k_diffusivity<<<gD, blk, 0, stream>>>(H, zc, Dbuf, scal);
        k_dt<<<1, 1, 0, stream>>>(scal);
        k_update<<<gU, blk, 0, stream>>>(Dbuf, zc, Zela, Ztopo, H, zn, scal);
        float* t = zc; zc = zn; zn = t;
    }
}

// Round 2
// 573.802 us; speedup vs baseline: 11.1227x; 11.1227x over previous
//
#include <hip/hip_runtime.h>

#define NN 1024
#define NM1 1023
#define DXF 100.0f
#define EPSF 1e-20f
#define NPART 4096   // (16 x 256) blocks in k_diffusivity

// FD * (RHO*G)^3, computed in double like Python, cast to f32 once (JAX weak-scalar semantics)
constexpr double RG_ = 910.0 * 9.81;
constexpr float CFD = (float)(1e-16 * (RG_ * RG_ * RG_));

__device__ __forceinline__ float wave_max(float v) {
    #pragma unroll
    for (int off = 32; off > 0; off >>= 1)
        v = fmaxf(v, __shfl_down(v, off, 64));
    return v;
}

// scal[1] = t, scal[2] = dt
__global__ void k_init(const float* __restrict__ Hin, const float* __restrict__ Ztopo,
                       float* __restrict__ H, float* __restrict__ Zs, float* scal) {
    int idx = blockIdx.x * blockDim.x + threadIdx.x;
    if (idx < NN * NN) {
        float h = Hin[idx];
        H[idx] = h;
        Zs[idx] = Ztopo[idx] + h;
    }
    if (idx == 0) {
        scal[1] = 1880.0f;  // t = T0
    }
}

__global__ void k_diffusivity(const float* __restrict__ H, const float* __restrict__ Zs,
                              float* __restrict__ D, float* __restrict__ part) {
    int j = blockIdx.x * blockDim.x + threadIdx.x;
    int i = blockIdx.y * blockDim.y + threadIdx.y;
    float d = 0.0f;
    if (i < NM1 && j < NM1) {
        const float* Zr0 = Zs + i * NN;
        const float* Zr1 = Zr0 + NN;
        const float* Hr0 = H + i * NN;
        const float* Hr1 = Hr0 + NN;
        // reference op order: 0.25*(((H00 + H11) + H01) + H10)
        float havg = 0.25f * (((Hr0[j] + Hr1[j + 1]) + Hr0[j + 1]) + Hr1[j]);
        float sx = 0.5f * ((Zr0[j + 1] - Zr0[j]) / DXF + (Zr1[j + 1] - Zr1[j]) / DXF);
        float sy = 0.5f * ((Zr1[j] - Zr0[j]) / DXF + (Zr1[j + 1] - Zr0[j + 1]) / DXF);
        float sn = sqrtf(sx * sx + sy * sy + EPSF);
        float h2 = havg * havg;
        float h4 = h2 * h2;
        float h5 = h4 * havg;   // pow(x,5) by squaring, like XLA
        d = CFD * h5 * (sn * sn) + EPSF;
        D[i * NM1 + j] = d;
    }
    // block-level max -> one plain store per block (no contended atomics)
    __shared__ float red[4];
    float m = wave_max(d);
    int tid = threadIdx.y * blockDim.x + threadIdx.x;
    if ((tid & 63) == 0) red[tid >> 6] = m;
    __syncthreads();
    if (tid == 0) {
        float mx = fmaxf(fmaxf(red[0], red[1]), fmaxf(red[2], red[3]));
        part[blockIdx.y * gridDim.x + blockIdx.x] = mx;
    }
}

__global__ void k_dt(const float* __restrict__ part, float* scal) {
    __shared__ float red[16];
    float m = 0.0f;
    for (int i = threadIdx.x; i < NPART; i += 1024) m = fmaxf(m, part[i]);
    m = wave_max(m);
    if ((threadIdx.x & 63) == 0) red[threadIdx.x >> 6] = m;
    __syncthreads();
    if (threadIdx.x == 0) {
        float mx = red[0];
        #pragma unroll
        for (int w = 1; w < 16; ++w) mx = fmaxf(mx, red[w]);
        float dt = fminf(10000.0f / (2.7f * mx), 1.0f);
        float t = scal[1];
        if (!(t < 1900.0f)) dt = 0.0f;
        scal[2] = dt;
        scal[1] = t + dt;
    }
}

__global__ void k_update(const float* __restrict__ D, const float* __restrict__ Zs,
                         const float* __restrict__ Zela, const float* __restrict__ Ztopo,
                         float* __restrict__ H, float* __restrict__ Zn,
                         const float* scal) {
    int j = blockIdx.x * blockDim.x + threadIdx.x;
    int i = blockIdx.y * blockDim.y + threadIdx.y;
    if (i >= NN || j >= NN) return;
    int idx = i * NN + j;
    float h = H[idx];
    if (i >= 1 && i <= NN - 2 && j >= 1 && j <= NN - 2) {
        float dt = scal[2];
        const float* Drm = D + (i - 1) * NM1;
        const float* Dr0 = D + i * NM1;
        float Dmm = Drm[j - 1], Dm0 = Drm[j];
        float D0m = Dr0[j - 1], D00 = Dr0[j];
        const float* Zrm = Zs + (i - 1) * NN;
        const float* Zr0 = Zs + i * NN;
        const float* Zrp = Zs + (i + 1) * NN;
        float z00 = Zr0[j];
        // qx[i-1][j], qx[i-1][j-1]
        float qxr = -(0.5f * (Dm0 + D00)) * (Zr0[j + 1] - z00) / DXF;
        float qxl = -(0.5f * (Dmm + D0m)) * (z00 - Zr0[j - 1]) / DXF;
        // qy[i][j-1], qy[i-1][j-1]
        float qyd = -(0.5f * (D0m + D00)) * (Zrp[j] - z00) / DXF;
        float qyu = -(0.5f * (Dmm + Dm0)) * (z00 - Zrm[j]) / DXF;
        float dHdt = -((qxr - qxl) / DXF + (qyd - qyu) / DXF);
        float b = fminf(1e-3f * (z00 - Zela[idx]), 0.3f);
        h = h + dt * (dHdt + b);
    }
    h = fmaxf(h, 0.0f);
    H[idx] = h;
    Zn[idx] = Ztopo[idx] + h;
}

extern "C" void kernel_launch(void* const* d_in, const int* in_sizes, int n_in,
                              void* d_out, int out_size, void* d_ws, size_t ws_size,
                              hipStream_t stream) {
    const float* Zela  = (const float*)d_in[0];
    const float* Ztopo = (const float*)d_in[1];
    const float* Hin   = (const float*)d_in[2];
    float* H = (float*)d_out;

    float* w    = (float*)d_ws;
    float* scal = w;                       // 16 floats reserved
    float* part = w + 16;                  // NPART floats
    float* Dbuf = part + NPART;            // (N-1)^2, padded into N^2 slot
    float* ZA   = Dbuf + NN * NN;
    float* ZB   = ZA + NN * NN;

    dim3 b1(256), g1((NN * NN + 255) / 256);
    k_init<<<g1, b1, 0, stream>>>(Hin, Ztopo, H, ZA, scal);

    dim3 blk(64, 4);
    dim3 gD((NM1 + 63) / 64, (NM1 + 3) / 4);   // 16 x 256 = NPART blocks
    dim3 gU((NN + 63) / 64, (NN + 3) / 4);

    float* zc = ZA;
    float* zn = ZB;
    for (int s = 0; s < 32; ++s) {
        k_diffusivity<<<gD, blk, 0, stream>>>(H, zc, Dbuf, part);
        k_dt<<<1, 1024, 0, stream>>>(part, scal);
        k_update<<<gU, blk, 0, stream>>>(Dbuf, zc, Zela, Ztopo, H, zn, scal);
        float* t = zc; zc = zn; zn = t;
    }
}